// Round 17
// baseline (196.872 us; speedup 1.0000x reference)
//
#include <hip/hip_runtime.h>
#include <cstdint>
#include <cstddef>

#define NPTS 8192
#define NUM_CLASSES 5
#define XCOLS 10          // 3 coords + batch + feat + 5 seg
#define EPS2 225.0f
#define MIN_PTS 5
#define NGROUPS 10
#define BIGC 0x3fffffff

#define NLCAP 1536        // max nodes per group (expect ~820)
#define NSLICE 8          // row slices (blocks) per group
#define SROWS 192         // rows per slice (contiguous!)
#define SCAP 4096         // per-(group,slice) private edge capacity
#define EACAP 12288       // LDS edge cap in graph phase (expect ~5.4k)
#define ROUNDS 16
#define DPAD 16           // done[] padding (64 B apart)

// ---- group id of point i from raw x row (strict > = jnp.argmax) ----
__device__ __forceinline__ int group_of(const float* __restrict__ x, int i) {
    const float* r = x + (size_t)i * XCOLS;
    int b = (int)r[3];
    float best = r[5]; int bc = 0;
    #pragma unroll
    for (int c = 1; c < NUM_CLASSES; c++) {
        float v = r[5 + c];
        if (v > best) { best = v; bc = c; }
    }
    return b * NUM_CLASSES + bc;
}

// ---------------- nodes: ordered per-group node list (once per group) --------
__global__ void __launch_bounds__(1024) k_nodes(
        const float* __restrict__ x, int* __restrict__ nlist_g,
        int* __restrict__ nn_g, unsigned int* __restrict__ done) {
    __shared__ unsigned long long masks[NPTS / 64];   // 128 words
    __shared__ int pref[NPTS / 64];
    __shared__ int nnS;
    const int g = blockIdx.x;
    const int tid = threadIdx.x, lane = tid & 63, wv = tid >> 6;

    if (tid == 0) done[g * DPAD] = 0u;
    for (int w = wv; w < NPTS / 64; w += 16) {
        int i = w * 64 + lane;
        unsigned long long bm = __ballot(group_of(x, i) == g);
        if (lane == 0) masks[w] = bm;
    }
    __syncthreads();
    if (wv == 0) {                         // 2-chunk scan of 128 popcounts
        int v0 = __popcll(masks[lane]);
        int incl = v0;
        #pragma unroll
        for (int s = 1; s < 64; s <<= 1) {
            int o = __shfl_up(incl, s);
            if (lane >= s) incl += o;
        }
        pref[lane] = incl - v0;
        int tot0 = __shfl(incl, 63);
        int v1 = __popcll(masks[64 + lane]);
        int incl1 = v1;
        #pragma unroll
        for (int s = 1; s < 64; s <<= 1) {
            int o = __shfl_up(incl1, s);
            if (lane >= s) incl1 += o;
        }
        pref[64 + lane] = tot0 + incl1 - v1;
        if (lane == 63) nnS = tot0 + incl1;
    }
    __syncthreads();
    for (int w = wv; w < NPTS / 64; w += 16) {
        int i = w * 64 + lane;
        unsigned long long bm = masks[w];
        if ((bm >> lane) & 1ull) {
            int p = pref[w] + __popcll(bm & ((1ull << lane) - 1ull));
            if (p < NLCAP) nlist_g[g * NLCAP + p] = i;
        }
    }
    if (tid == 0) nn_g[g] = (nnS > NLCAP) ? NLCAP : nnS;
}

// ---------------- fused pairs + (8th arriver) graph --------------------------
// grid = 10 groups x 8 slices; block 1024 thr (16 waves). Slice s owns
// CONTIGUOUS rows [s*192, s*192+192): qu gathers are lane-consecutive
// (conflict-free), emission/deg single-writer per row.
__global__ void __launch_bounds__(1024) k_fused2(
        const float* __restrict__ x, const int* __restrict__ nlist_g,
        const int* __restrict__ nn_g,
        unsigned int* __restrict__ edges,     // (g*8+s)*SCAP private slices
        int* __restrict__ ecnt,               // 80 counts (single writer each)
        int* __restrict__ deg_g,              // 10*NLCAP full degrees
        unsigned int* __restrict__ done,
        float* __restrict__ out) {
    __shared__ float4 pts[NLCAP];                     // 24 KB
    __shared__ int nlist[NLCAP];                      // 6 KB
    __shared__ int srowdeg[SROWS];                    // 768 B
    __shared__ int sdeg[NLCAP];                       // 6 KB -> cid array later
    __shared__ int spar[NLCAP];                       // 6 KB
    __shared__ int sbmin[NLCAP];                      // 6 KB
    __shared__ unsigned int eA[EACAP];                // 48 KB
    __shared__ unsigned long long corebm[NLCAP/64];   // 192 B
    __shared__ unsigned long long repbm[NLCAP/64];    // 192 B
    __shared__ int flags[ROUNDS];
    __shared__ int lcnt, iswin, eoff[NSLICE + 1];

    const int g = blockIdx.x / NSLICE;
    const int s = blockIdx.x % NSLICE;
    const int tid = threadIdx.x, lane = tid & 63, wv = tid >> 6;
    const int nn = nn_g[g];
    const int R0 = s * SROWS;

    // ---- Phase B: pair slice (skipped entirely if slice fully dead) ----
    if (tid == 0) lcnt = 0;
    if (R0 < nn) {
        for (int k = tid; k < NLCAP; k += 1024) {
            if (k < nn) {
                const float* r = x + (size_t)nlist_g[g * NLCAP + k] * XCOLS;
                float px = r[0], py = r[1], pz = r[2];
                pts[k] = make_float4(px, py, pz, px*px + py*py + pz*pz);
            } else {
                pts[k] = make_float4(0.f, 0.f, 0.f, 3.0e38f);  // never adjacent
            }
        }
        for (int m = tid; m < SROWS; m += 1024) srowdeg[m] = 0;
        __syncthreads();

        int rrow[3]; float4 qu[3]; int rowdeg[3];
        #pragma unroll
        for (int k = 0; k < 3; k++) {
            rrow[k] = R0 + lane + 64 * k;             // lane-consecutive
            qu[k] = pts[rrow[k]];                     // conflict-free gather
            rowdeg[k] = 0;
        }
        const int NC = (nn + 31) >> 5;
        unsigned int* eg = edges + (size_t)(g * NSLICE + s) * SCAP;
        for (int c = wv; c < NC; c += 16) {           // wave wv owns c==wv mod 16
            int base = c << 5;
            unsigned int bits[3] = {0u, 0u, 0u};
            #pragma unroll
            for (int t = 0; t < 32; t++) {
                float4 qv = pts[base + t];            // wave-uniform broadcast
                #pragma unroll
                for (int k = 0; k < 3; k++) {
                    float d2 = qu[k].w + qv.w - 2.0f * (qu[k].x*qv.x + qu[k].y*qv.y + qu[k].z*qv.z);
                    bits[k] |= (d2 < EPS2) ? (1u << t) : 0u;
                }
            }
            int cnt = 0;
            #pragma unroll
            for (int k = 0; k < 3; k++) {
                rowdeg[k] += __popc(bits[k]);         // FULL adjacency (incl self)
                int d = rrow[k] - base;               // emission: keep v > u
                if (d >= 31) bits[k] = 0u;
                else if (d >= 0) bits[k] &= ~((2u << d) - 1u);
                cnt += __popc(bits[k]);
            }
            int incl = cnt;
            #pragma unroll
            for (int st = 1; st < 64; st <<= 1) {
                int o = __shfl_up(incl, st);
                if (lane >= st) incl += o;
            }
            int tot = __shfl(incl, 63);
            if (tot > 0) {
                int rbase = 0;
                if (lane == 63) rbase = atomicAdd(&lcnt, tot);   // LDS atomic
                rbase = __shfl(rbase, 63);
                int p = rbase + incl - cnt;
                #pragma unroll
                for (int k = 0; k < 3; k++) {
                    unsigned int b = bits[k];
                    unsigned int uhi = (unsigned int)rrow[k] << 11;
                    while (b) {
                        int t = __ffs(b) - 1; b &= b - 1;
                        if (p < SCAP) eg[p] = uhi | (unsigned int)(base + t);
                        p++;
                    }
                }
            }
        }
        #pragma unroll
        for (int k = 0; k < 3; k++)
            if (rowdeg[k] > 0) atomicAdd(&srowdeg[lane + 64 * k], rowdeg[k]);
        __syncthreads();
        for (int m = tid; m < SROWS; m += 1024)       // single writer per row
            deg_g[g * NLCAP + R0 + m] = srowdeg[m];
    }
    if (tid == 0) ecnt[g * NSLICE + s] = (lcnt > SCAP) ? SCAP : lcnt;

    // ---- arrival: release, 8th arriver runs the graph phase ----
    __syncthreads();
    __threadfence();                                   // device-scope release
    if (tid == 0) {
        unsigned int old = __hip_atomic_fetch_add(&done[g * DPAD], 1u,
                              __ATOMIC_ACQ_REL, __HIP_MEMORY_SCOPE_AGENT);
        iswin = (old == NSLICE - 1) ? 1 : 0;
    }
    __syncthreads();
    if (!iswin) return;
    __threadfence();                                   // acquire side

    // ---- Phase C: graph (winner block only) ----
    const int NN = nn;
    if (tid < ROUNDS) flags[tid] = 0;
    if (tid < NSLICE) eoff[tid + 1] = ecnt[g * NSLICE + tid];
    if (tid == 0) eoff[0] = 0;
    for (int k = tid; k < NLCAP; k += 1024) {
        sdeg[k] = (k < NN) ? deg_g[g * NLCAP + k] : 0;
        spar[k] = k;
        sbmin[k] = BIGC;
        nlist[k] = nlist_g[g * NLCAP + k];
    }
    __syncthreads();
    if (tid == 0) {
        #pragma unroll
        for (int t = 0; t < NSLICE; t++) {
            int v2 = eoff[t] + eoff[t + 1];
            eoff[t + 1] = (v2 > EACAP) ? EACAP : v2;
        }
    }
    __syncthreads();
    for (int s2 = 0; s2 < NSLICE; s2++) {
        int o0 = eoff[s2], cnt = eoff[s2 + 1] - o0;
        const unsigned int* src = edges + (size_t)(g * NSLICE + s2) * SCAP;
        for (int k = tid; k < cnt; k += 1024) eA[o0 + k] = src[k];
    }
    __syncthreads();
    const int NA = eoff[NSLICE];

    // core bitmap
    for (int w = wv; w < NLCAP / 64; w += 16) {
        int l = w * 64 + lane;
        bool isc = (l < NN) && (sdeg[l] >= MIN_PTS);
        unsigned long long bm = __ballot(isc);
        if (lane == 0) corebm[w] = bm;
    }
    __syncthreads();
    auto corebit = [&](int l) -> bool { return (corebm[l >> 6] >> (l & 63)) & 1ull; };

    // SV rounds: corebit-gated hook-to-min + double pointer jump
    for (int r = 0; r < ROUNDS; r++) {
        for (int k = tid; k < NA; k += 1024) {
            unsigned int pk = eA[k];
            int u = (int)(pk >> 11), v = (int)(pk & 2047u);
            if (corebit(u) && corebit(v)) {
                int a = spar[u], b2 = spar[v];
                if (a < b2)      { int old = atomicMin(&spar[v], a);  if (old > a)  flags[r] = 1; }
                else if (b2 < a) { int old = atomicMin(&spar[u], b2); if (old > b2) flags[r] = 1; }
            }
        }
        __syncthreads();
        for (int k = tid; k < NN; k += 1024) {
            int p1 = spar[k]; int p2 = spar[p1];
            if (p2 < p1) { p1 = spar[p2]; spar[k] = (p1 < p2) ? p1 : p2; flags[r] = 1; }
        }
        __syncthreads();
        if (!flags[r]) break;
    }

    // reps + rank into sdeg (wave 0 serial over 24 words)
    for (int w = wv; w < NLCAP / 64; w += 16) {
        int l = w * 64 + lane;
        bool isr = (l < NN) && corebit(l) && (spar[l] == l);
        unsigned long long bm = __ballot(isr);
        if (lane == 0) repbm[w] = bm;
    }
    __syncthreads();
    if (wv == 0) {
        int running = 0;
        for (int w = 0; w < NLCAP / 64; w++) {
            unsigned long long bm = repbm[w];
            if ((bm >> lane) & 1ull)
                sdeg[w * 64 + lane] = running + __popcll(bm & ((1ull << lane) - 1ull));
            running += __popcll(bm);
        }
    }
    __syncthreads();
    // ccid -> overwrite spar
    int cc[2];
    #pragma unroll
    for (int t = 0; t < 2; t++) {
        int k = tid + t * 1024;
        cc[t] = (k < NN && corebit(k)) ? sdeg[spar[k]] : BIGC;
    }
    __syncthreads();
    #pragma unroll
    for (int t = 0; t < 2; t++) {
        int k = tid + t * 1024;
        if (k < NN) spar[k] = cc[t];
    }
    __syncthreads();
    // border: min adjacent core cid for the non-core endpoint
    for (int k = tid; k < NA; k += 1024) {
        unsigned int pk = eA[k];
        int u = (int)(pk >> 11), v = (int)(pk & 2047u);
        int cu = spar[u], cv = spar[v];
        if (cu == BIGC) { if (cv != BIGC) atomicMin(&sbmin[u], cv); }
        else if (cv == BIGC) atomicMin(&sbmin[v], cu);
    }
    __syncthreads();
    // final labels + clustered output
    for (int k = tid; k < NN; k += 1024) {
        int i = nlist[k];
        int c = spar[k];
        int lbl = (c != BIGC) ? c : ((sbmin[k] < BIGC) ? sbmin[k] : -1);
        out[i] = (float)lbl;
        const float* r = x + (size_t)i * XCOLS;
        float* o = out + NPTS + (size_t)i * 5;
        bool keep = lbl >= 0;
        #pragma unroll
        for (int c5 = 0; c5 < 5; c5++) o[c5] = keep ? r[c5] : 0.0f;
    }
}

extern "C" void kernel_launch(void* const* d_in, const int* in_sizes, int n_in,
                              void* d_out, int out_size, void* d_ws, size_t ws_size,
                              hipStream_t stream) {
    const float* x = (const float*)d_in[0];
    float* out = (float*)d_out;
    char* ws = (char*)d_ws;

    // workspace layout (~1.4 MB)
    unsigned int* done  = (unsigned int*)(ws);            // 640 B
    int* ecnt           = (int*)(ws + 1024);              // 320 B
    int* nn_g           = (int*)(ws + 2048);              // 64 B
    int* nlist_g        = (int*)(ws + 2112);              // 61440 B
    int* deg_g          = (int*)(ws + 63552);             // 61440 B
    unsigned int* edges = (unsigned int*)(ws + 124992);   // 80*4096*4 = 1.25 MB

    k_nodes <<<NGROUPS, 1024, 0, stream>>>(x, nlist_g, nn_g, done);
    k_fused2<<<NGROUPS * NSLICE, 1024, 0, stream>>>(x, nlist_g, nn_g, edges,
                                                    ecnt, deg_g, done, out);
}

// Round 18
// 103.741 us; speedup vs baseline: 1.8977x; 1.8977x over previous
//
#include <hip/hip_runtime.h>
#include <cstdint>
#include <cstddef>

#define NPTS 8192
#define NUM_CLASSES 5
#define XCOLS 10          // 3 coords + batch + feat + 5 seg
#define EPS2 225.0f
#define MIN_PTS 5
#define NGROUPS 10
#define BIGC 0x3fffffff

#define NLCAP 1536        // max nodes per group (expect ~820)
#define EACAP 8192        // per-group eps-pairs u<v (expect ~5.4k)
#define ELCAP 8192        // core-core edges
#define EBCAP 2048        // core-noncore edges (expect ~500)
#define CPAD 64           // per-group edge counters padded 256 B apart
#define NSLICE 8          // row slices per group in k_pairs
#define KR 3              // rows per lane in k_pairs (3*64*8 = 1536 = NLCAP)
#define ROUNDS 16

// ---------------- setup: pack coords+p2, group, zero edge counters -----------
__global__ void k_setup(const float* __restrict__ x, float4* __restrict__ q,
                        int* __restrict__ grp, unsigned int* __restrict__ gcnt) {
    int i = blockIdx.x * blockDim.x + threadIdx.x;
    if (i < NGROUPS * CPAD) gcnt[i] = 0u;
    if (i >= NPTS) return;
    const float* r = x + (size_t)i * XCOLS;
    float px = r[0], py = r[1], pz = r[2];
    int b = (int)r[3];
    float best = r[5]; int bc = 0;
    #pragma unroll
    for (int c = 1; c < NUM_CLASSES; c++) {
        float v = r[5 + c];
        if (v > best) { best = v; bc = c; }   // strict > keeps first max (jnp.argmax)
    }
    q[i] = make_float4(px, py, pz, px*px + py*py + pz*pz);
    grp[i] = b * NUM_CLASSES + bc;
}

// ---------------- nodes: ordered per-group node list (parallel prefix) -------
__global__ void __launch_bounds__(1024) k_nodes(
        const int* __restrict__ grp, int* __restrict__ nlist_g,
        int* __restrict__ nn_g) {
    __shared__ unsigned long long masks[NPTS / 64];   // 128 words
    __shared__ int pref[NPTS / 64];
    __shared__ int nnS;
    const int g = blockIdx.x;
    const int tid = threadIdx.x, lane = tid & 63, wv = tid >> 6;

    for (int w = wv; w < NPTS / 64; w += 16) {
        int i = w * 64 + lane;
        unsigned long long bm = __ballot(grp[i] == g);
        if (lane == 0) masks[w] = bm;
    }
    __syncthreads();
    if (wv == 0) {                         // 2-chunk scan of 128 popcounts
        int v0 = __popcll(masks[lane]);
        int incl = v0;
        #pragma unroll
        for (int s = 1; s < 64; s <<= 1) {
            int o = __shfl_up(incl, s);
            if (lane >= s) incl += o;
        }
        pref[lane] = incl - v0;
        int tot0 = __shfl(incl, 63);
        int v1 = __popcll(masks[64 + lane]);
        int incl1 = v1;
        #pragma unroll
        for (int s = 1; s < 64; s <<= 1) {
            int o = __shfl_up(incl1, s);
            if (lane >= s) incl1 += o;
        }
        pref[64 + lane] = tot0 + incl1 - v1;
        if (lane == 63) nnS = tot0 + incl1;
    }
    __syncthreads();
    for (int w = wv; w < NPTS / 64; w += 16) {
        int i = w * 64 + lane;
        unsigned long long bm = masks[w];
        if ((bm >> lane) & 1ull) {
            int p = pref[w] + __popcll(bm & ((1ull << lane) - 1ull));
            if (p < NLCAP) nlist_g[g * NLCAP + p] = i;
        }
    }
    if (tid == 0) nn_g[g] = (nnS > NLCAP) ? NLCAP : nnS;
}

// ---------------- pairs: per-(group,slice) adjacency -> global edges + deg ---
// grid = 10*8; block 256 (4 waves). Wave w owns chunks c==w (mod 4); lane owns
// rows s+8*(lane+64k), k<KR (compile-time -> registers). Each ds_read feeds
// 64 lanes x 3 rows.
__global__ void __launch_bounds__(256) k_pairs(
        const float4* __restrict__ q, const int* __restrict__ nlist_g,
        const int* __restrict__ nn_g, unsigned int* __restrict__ eAll_g,
        unsigned int* __restrict__ gcnt, int* __restrict__ deg_g) {
    __shared__ float4 pts[NLCAP];          // 24 KB
    __shared__ int srowdeg[NLCAP / NSLICE];// 192 rows this slice
    const int g = blockIdx.x / NSLICE;
    const int s = blockIdx.x % NSLICE;
    const int tid = threadIdx.x, lane = tid & 63, wq = tid >> 6;
    const int nn = nn_g[g];

    for (int k = tid; k < NLCAP; k += 256)
        pts[k] = (k < nn) ? q[nlist_g[g * NLCAP + k]]
                          : make_float4(0.f, 0.f, 0.f, 3.0e38f);
    for (int m = tid; m < NLCAP / NSLICE; m += 256) srowdeg[m] = 0;
    __syncthreads();

    int rrow[KR]; float4 qu[KR]; int rowdeg[KR];
    #pragma unroll
    for (int k = 0; k < KR; k++) {
        rrow[k] = s + 8 * (lane + 64 * k);           // < 1536
        qu[k] = pts[rrow[k]];                        // sentinel-safe
        rowdeg[k] = 0;
    }

    const int NC = (nn + 31) >> 5;
    unsigned int* eg = eAll_g + (size_t)g * EACAP;
    for (int c = wq; c < NC; c += 4) {
        int base = c << 5;
        unsigned int bits[KR];
        #pragma unroll
        for (int k = 0; k < KR; k++) bits[k] = 0u;
        #pragma unroll
        for (int t = 0; t < 32; t++) {
            float4 qv = pts[base + t];               // wave-uniform broadcast
            #pragma unroll
            for (int k = 0; k < KR; k++) {
                float d2 = qu[k].w + qv.w - 2.0f * (qu[k].x*qv.x + qu[k].y*qv.y + qu[k].z*qv.z);
                bits[k] |= (d2 < EPS2) ? (1u << t) : 0u;
            }
        }
        int cnt = 0;
        #pragma unroll
        for (int k = 0; k < KR; k++) {
            int d = rrow[k] - base;                  // keep only v > u
            if (d >= 31) bits[k] = 0u;
            else if (d >= 0) bits[k] &= ~((2u << d) - 1u);
            int pc = __popc(bits[k]);
            rowdeg[k] += pc;
            cnt += pc;
        }
        int incl = cnt;
        #pragma unroll
        for (int st = 1; st < 64; st <<= 1) {
            int o = __shfl_up(incl, st);
            if (lane >= st) incl += o;
        }
        int tot = __shfl(incl, 63);
        if (tot > 0) {
            unsigned int rbase = 0;
            if (lane == 63) rbase = atomicAdd(&gcnt[g * CPAD], (unsigned int)tot);
            rbase = __shfl(rbase, 63);
            unsigned int p = rbase + (unsigned int)(incl - cnt);
            #pragma unroll
            for (int k = 0; k < KR; k++) {
                unsigned int b = bits[k];
                unsigned int uhi = (unsigned int)rrow[k] << 11;
                while (b) {
                    int t = __ffs(b) - 1; b &= b - 1;
                    if (p < EACAP) eg[p] = uhi | (unsigned int)(base + t);
                    p++;
                }
            }
        }
    }
    #pragma unroll
    for (int k = 0; k < KR; k++)
        if (rowdeg[k] > 0) atomicAdd(&srowdeg[lane + 64 * k], rowdeg[k]);
    __syncthreads();
    // this block is the unique owner of rows r==s (mod 8): plain store
    for (int m = tid; m < NLCAP / NSLICE; m += 256)
        deg_g[g * NLCAP + s + 8 * m] = 1 + srowdeg[m];   // +1 self-adjacency
}

// ---------------- graph: deg -> core -> SV -> rank -> border -> output -------
__global__ void __launch_bounds__(1024) k_graph(
        const unsigned int* __restrict__ eAll_g, const unsigned int* __restrict__ gcnt,
        const int* __restrict__ deg_g, const int* __restrict__ nlist_g,
        const int* __restrict__ nn_g, const float* __restrict__ x,
        float* __restrict__ out) {
    __shared__ unsigned int eA[EACAP];               // 32 KB
    __shared__ unsigned int eL[ELCAP];               // 32 KB
    __shared__ unsigned int eB[EBCAP];               // 8 KB
    __shared__ int sdeg[NLCAP];                      // 6 KB
    __shared__ int spar[NLCAP];                      // 6 KB
    __shared__ int scid[NLCAP];                      // 6 KB
    __shared__ int sbmin[NLCAP];                     // 6 KB
    __shared__ int nlist[NLCAP];                     // 6 KB
    __shared__ unsigned long long corebm[NLCAP/64];  // 192 B
    __shared__ unsigned long long repbm[NLCAP/64];   // 192 B
    __shared__ int nL, nB, sflag;

    const int g = blockIdx.x;
    const int tid = threadIdx.x, lane = tid & 63, wv = tid >> 6;
    const int NN = nn_g[g];
    unsigned int Eu = gcnt[g * CPAD];
    const int NA = (Eu > (unsigned)EACAP) ? EACAP : (int)Eu;

    if (tid == 0) { nL = 0; nB = 0; }
    for (int k = tid; k < NLCAP; k += 1024) {
        sdeg[k] = deg_g[g * NLCAP + k];
        spar[k] = k;
        sbmin[k] = BIGC;
        nlist[k] = nlist_g[g * NLCAP + k];
    }
    for (int e = tid; e < NA; e += 1024) eA[e] = eAll_g[(size_t)g * EACAP + e];
    __syncthreads();
    // v-side degrees
    for (int e = tid; e < NA; e += 1024) atomicAdd(&sdeg[eA[e] & 2047u], 1);
    __syncthreads();
    // core bitmap
    for (int w = wv; w < NLCAP / 64; w += 16) {
        int l = w * 64 + lane;
        bool isc = (l < NN) && (sdeg[l] >= MIN_PTS);
        unsigned long long bm = __ballot(isc);
        if (lane == 0) corebm[w] = bm;
    }
    __syncthreads();
    auto corebit = [&](int l) -> bool { return (corebm[l >> 6] >> (l & 63)) & 1ull; };

    // classify eA -> eL / eB (wave-aggregated)
    for (int e0 = 0; e0 < NA; e0 += 1024) {
        int e = e0 + tid;
        unsigned int pk = (e < NA) ? eA[e] : 0u;
        bool val = (e < NA);
        int u = (int)(pk >> 11), v = (int)(pk & 2047u);
        bool cu = val && corebit(u), cv = val && corebit(v);
        bool isL = cu && cv, isB = val && (cu != cv);
        unsigned long long mL = __ballot(isL);
        if (mL) {
            int b0 = 0;
            if (lane == 0) b0 = atomicAdd(&nL, __popcll(mL));
            b0 = __shfl(b0, 0);
            if (isL) {
                int idx = b0 + __popcll(mL & ((1ull << lane) - 1ull));
                if (idx < ELCAP) eL[idx] = pk;
            }
        }
        unsigned long long mB = __ballot(isB);
        if (mB) {
            int b0 = 0;
            if (lane == 0) b0 = atomicAdd(&nB, __popcll(mB));
            b0 = __shfl(b0, 0);
            if (isB) {
                int idx = b0 + __popcll(mB & ((1ull << lane) - 1ull));
                if (idx < EBCAP) eB[idx] = pk;
            }
        }
    }
    __syncthreads();
    const int NL = (nL > ELCAP) ? ELCAP : nL;
    const int NB = (nB > EBCAP) ? EBCAP : nB;

    // SV rounds: hook-to-min + DOUBLE pointer jump
    for (int r = 0; r < ROUNDS; r++) {
        if (tid == 0) sflag = 0;
        __syncthreads();
        for (int k = tid; k < NL; k += 1024) {
            unsigned int pk = eL[k];
            int u = (int)(pk >> 11), v = (int)(pk & 2047u);
            int a = spar[u], b2 = spar[v];
            if (a < b2)      { int old = atomicMin(&spar[v], a);  if (old > a)  sflag = 1; }
            else if (b2 < a) { int old = atomicMin(&spar[u], b2); if (old > b2) sflag = 1; }
        }
        __syncthreads();
        for (int k = tid; k < NN; k += 1024) {
            int s = spar[k]; int s2 = spar[s];
            if (s2 < s) { s = spar[s2]; spar[k] = (s < s2) ? s : s2; sflag = 1; }
        }
        __syncthreads();
        if (!sflag) break;
    }

    // reps + rank (wave 0 serial over 24 words)
    for (int w = wv; w < NLCAP / 64; w += 16) {
        int l = w * 64 + lane;
        bool isr = (l < NN) && corebit(l) && (spar[l] == l);
        unsigned long long bm = __ballot(isr);
        if (lane == 0) repbm[w] = bm;
    }
    __syncthreads();
    if (wv == 0) {
        int running = 0;
        for (int w = 0; w < NLCAP / 64; w++) {
            unsigned long long bm = repbm[w];
            if ((bm >> lane) & 1ull)
                scid[w * 64 + lane] = running + __popcll(bm & ((1ull << lane) - 1ull));
            running += __popcll(bm);
        }
    }
    __syncthreads();
    // ccid -> overwrite spar
    int cc[2];
    #pragma unroll
    for (int t = 0; t < 2; t++) {
        int k = tid + t * 1024;
        cc[t] = (k < NN && corebit(k)) ? scid[spar[k]] : BIGC;
    }
    __syncthreads();
    #pragma unroll
    for (int t = 0; t < 2; t++) {
        int k = tid + t * 1024;
        if (k < NN) spar[k] = cc[t];
    }
    __syncthreads();
    // border: min adjacent core cid for the non-core endpoint
    for (int k = tid; k < NB; k += 1024) {
        unsigned int pk = eB[k];
        int u = (int)(pk >> 11), v = (int)(pk & 2047u);
        int cu = spar[u], cv = spar[v];
        if (cu == BIGC) atomicMin(&sbmin[u], cv);
        else            atomicMin(&sbmin[v], cu);
    }
    __syncthreads();
    // final labels + clustered output
    for (int k = tid; k < NN; k += 1024) {
        int i = nlist[k];
        int c = spar[k];
        int lbl = (c != BIGC) ? c : ((sbmin[k] < BIGC) ? sbmin[k] : -1);
        out[i] = (float)lbl;
        const float* r = x + (size_t)i * XCOLS;
        float* o = out + NPTS + (size_t)i * 5;
        bool keep = lbl >= 0;
        #pragma unroll
        for (int c5 = 0; c5 < 5; c5++) o[c5] = keep ? r[c5] : 0.0f;
    }
}

extern "C" void kernel_launch(void* const* d_in, const int* in_sizes, int n_in,
                              void* d_out, int out_size, void* d_ws, size_t ws_size,
                              hipStream_t stream) {
    const float* x = (const float*)d_in[0];
    float* out = (float*)d_out;
    char* ws = (char*)d_ws;

    // workspace layout (~660 KB)
    float4* q           = (float4*)(ws);                  // 131072 B
    int* grp            = (int*)(ws + 131072);            // 32768
    unsigned int* gcnt  = (unsigned int*)(ws + 163840);   // 10*64*4 = 2560
    int* nn_g           = (int*)(ws + 166400);            // 64
    int* nlist_g        = (int*)(ws + 166464);            // 10*1536*4 = 61440
    int* deg_g          = (int*)(ws + 227904);            // 61440
    unsigned int* eAll_g= (unsigned int*)(ws + 289344);   // 10*8192*4 = 327680

    k_setup<<<NPTS / 256, 256, 0, stream>>>(x, q, grp, gcnt);
    k_nodes<<<NGROUPS, 1024, 0, stream>>>(grp, nlist_g, nn_g);
    k_pairs<<<NGROUPS * NSLICE, 256, 0, stream>>>(q, nlist_g, nn_g, eAll_g, gcnt, deg_g);
    k_graph<<<NGROUPS, 1024, 0, stream>>>(eAll_g, gcnt, deg_g, nlist_g, nn_g, x, out);
}